// Round 11
// baseline (577.562 us; speedup 1.0000x reference)
//
#include <hip/hip_runtime.h>

static constexpr int kN = 100000;
static constexpr int kE = 1600000;
static constexpr float kEps = 1e-5f;

static constexpr int kBSH = 9;                          // 512 nodes per bucket
static constexpr int kNB = (kN + 511) >> kBSH;          // 196 buckets
static constexpr int kBCAP = 12288;                     // staging cap per bucket
static constexpr int kCHUNK = 4096;                     // edges per bin_k block
static constexpr int kPad = 16;                         // degree padding quantum

typedef __attribute__((ext_vector_type(8))) short short8;   // 8 bf16 = 4 VGPRs
typedef __attribute__((ext_vector_type(4))) float float4v;  // MFMA acc
typedef __attribute__((ext_vector_type(2))) float float2v;

static __device__ inline unsigned short f2bf(float f) {
  union { float f; unsigned int u; } v; v.f = f;
  unsigned int r = v.u + 0x7fffu + ((v.u >> 16) & 1u);  // RNE
  return (unsigned short)(r >> 16);
}
static __device__ inline float bf2f(unsigned int bits16) {
  union { unsigned int u; float f; } v; v.u = bits16 << 16; return v.f;
}
static __device__ inline unsigned int pack2bf(float lo, float hi) {
  return (unsigned int)f2bf(lo) | ((unsigned int)f2bf(hi) << 16);
}

// ---------------------------------------------------------------- binning (phase 1)
__global__ __launch_bounds__(256) void bin_k(const int* __restrict__ src,
                                             const int* __restrict__ dst,
                                             int* __restrict__ deg,
                                             int* __restrict__ counter,
                                             int* __restrict__ gcursor,
                                             int2* __restrict__ gstage) {
  __shared__ int s_cnt[256];
  __shared__ int s_scan[256];
  __shared__ int s_base[256];
  __shared__ int s_cur[256];
  __shared__ int s_gb[256];
  __shared__ int2 s_stage[kCHUNK];
  int tid = threadIdx.x;
  if (blockIdx.x == 0 && tid == 0) *counter = 0;
  int e0 = blockIdx.x * kCHUNK;
  int n = kE - e0; if (n > kCHUNK) n = kCHUNK;
  s_cnt[tid] = 0;
  __syncthreads();
  for (int j = tid; j < n; j += 256) {
    int d = dst[e0 + j];
    atomicAdd(&s_cnt[d >> kBSH], 1);
    atomicAdd(&deg[d], 1);
  }
  __syncthreads();
  int v = s_cnt[tid];
  s_scan[tid] = v;
  __syncthreads();
  #pragma unroll
  for (int o = 1; o < 256; o <<= 1) {
    int t = (tid >= o) ? s_scan[tid - o] : 0;
    __syncthreads();
    s_scan[tid] += t;
    __syncthreads();
  }
  int excl = s_scan[tid] - v;
  s_base[tid] = excl;
  s_cur[tid] = excl;
  __syncthreads();
  if (tid < kNB && s_cnt[tid] > 0) s_gb[tid] = atomicAdd(&gcursor[tid], s_cnt[tid]);
  for (int j = tid; j < n; j += 256) {
    int s = src[e0 + j];
    int d = dst[e0 + j];
    int p = atomicAdd(&s_cur[d >> kBSH], 1);
    s_stage[p] = make_int2(s, d);
  }
  __syncthreads();
  for (int j = tid; j < n; j += 256) {
    int2 e = s_stage[j];
    int b = e.y >> kBSH;
    gstage[(size_t)b * kBCAP + s_gb[b] + (j - s_base[b])] = e;
  }
}

// row starts via wave-scan bump allocation over PADDED degrees; also dinv.
__global__ void alloc_rows_k(const int* __restrict__ deg, int* __restrict__ row_start,
                             int* __restrict__ counter, float* __restrict__ dinv) {
  int i = blockIdx.x * blockDim.x + threadIdx.x;
  int lane = threadIdx.x & 63;
  int d = (i < kN) ? deg[i] : 0;
  int pd = (d + kPad - 1) & ~(kPad - 1);  // padded degree
  int x = pd;
  #pragma unroll
  for (int off = 1; off < 64; off <<= 1) {
    int y = __shfl_up(x, off, 64);
    if (lane >= off) x += y;
  }
  int total = __shfl(x, 63, 64);
  int base = 0;
  if (lane == 63) base = atomicAdd(counter, total);
  base = __shfl(base, 63, 64);
  int start = base + x - pd;
  if (i < kN) {
    row_start[i] = start;
    dinv[i] = rsqrtf((float)(d + 1));
  }
}

// ---------------------------------------------------------------- scatter (phase 2)
__global__ __launch_bounds__(256) void scatter2_k(const int2* __restrict__ gstage,
                                                  const int* __restrict__ gcursor,
                                                  const int* __restrict__ rowst,
                                                  const int* __restrict__ deg,
                                                  int* __restrict__ csr_src) {
  __shared__ int s_cur[1 << kBSH];
  int b = blockIdx.x, tid = threadIdx.x;
  int n0 = b << kBSH;
  int nn = kN - n0; if (nn > (1 << kBSH)) nn = 1 << kBSH;
  for (int i = tid; i < nn; i += 256) s_cur[i] = rowst[n0 + i];
  __syncthreads();
  int cnt = gcursor[b];
  const int2* seg = gstage + (size_t)b * kBCAP;
  for (int j = tid; j < cnt; j += 256) {
    int2 e = seg[j];
    int pos = atomicAdd(&s_cur[e.y - n0], 1);
    csr_src[pos] = e.x;
  }
  __syncthreads();
  // pad: fill [rowst+deg, rowst+pdeg) with dummy index kN
  for (int i = tid; i < nn; i += 256) {
    int d = deg[n0 + i];
    int endp = rowst[n0 + i] + ((d + kPad - 1) & ~(kPad - 1));
    for (int p = s_cur[i]; p < endp; ++p) csr_src[p] = kN;
  }
}

// ---------------------------------------------------------------- weight convert + dummy-row zero
__global__ void convert_w_all_k(const float* __restrict__ W1, const float* __restrict__ W2,
                                const float* __restrict__ W3,
                                unsigned short* __restrict__ wf1,
                                unsigned short* __restrict__ wf2,
                                unsigned short* __restrict__ wf3,
                                unsigned char* __restrict__ hF8,
                                unsigned short* __restrict__ hH) {
  int tid = blockIdx.x * blockDim.x + threadIdx.x;
  const float* W;
  unsigned short* Wf;
  int BNO;
  if (tid < 2048) { W = W1; Wf = wf1; BNO = 128; }
  else if (tid < 4096) { W = W2; Wf = wf2; BNO = 128; tid -= 2048; }
  else if (tid < 5120) { W = W3; Wf = wf3; BNO = 64; tid -= 4096; }
  else if (tid < 5152) {  // zero dummy fp8 row (128B = 32 uints)
    ((unsigned int*)(hF8 + (size_t)kN * 128))[tid - 5120] = 0u;
    return;
  } else if (tid < 5184) {  // zero dummy bf16 row (128B = 32 uints)
    ((unsigned int*)(hH + (size_t)kN * 64))[tid - 5152] = 0u;
    return;
  } else return;
  int l = tid & 63;
  int frag = tid >> 6;
  int q = frag & 3;
  int t = frag >> 2;
  int n = t * 16 + (l & 15);
  int kbase = q * 32 + ((l >> 4) << 3);
  unsigned short v[8] __attribute__((aligned(16)));
  #pragma unroll
  for (int j = 0; j < 8; ++j) v[j] = f2bf(W[(kbase + j) * BNO + n]);
  ((uint4*)Wf)[tid] = *(const uint4*)v;
}

// ---------------------------------------------------------------- MFMA GEMM -> H' out
// Writes H'[r] = dinv[r] * (A@W)[r]; OUT8 ? fp8 e4m3 : bf16.
template <int BNO, bool AF32, bool OUT8>
__global__ __launch_bounds__(256) void gemm_mfma_k(const void* __restrict__ Aptr,
                                                   const unsigned short* __restrict__ Wf,
                                                   const float* __restrict__ dinv,
                                                   void* __restrict__ Cptr,
                                                   float* __restrict__ stats) {
  if (stats && blockIdx.x == 0) stats[threadIdx.x] = 0.f;
  int wid = (int)((blockIdx.x * blockDim.x + threadIdx.x) >> 6);
  if (wid >= kN / 16) return;  // 100000 = 16 * 6250
  int l = threadIdx.x & 63;
  int r0 = wid * 16;
  short8 a[4];
  if constexpr (AF32) {
    const float* Af = (const float*)Aptr + (size_t)(r0 + (l & 15)) * 128 + ((l >> 4) << 3);
    #pragma unroll
    for (int q = 0; q < 4; ++q) {
      float4 u0 = *(const float4*)(Af + q * 32);
      float4 u1 = *(const float4*)(Af + q * 32 + 4);
      short8 t;
      t[0] = (short)f2bf(u0.x); t[1] = (short)f2bf(u0.y);
      t[2] = (short)f2bf(u0.z); t[3] = (short)f2bf(u0.w);
      t[4] = (short)f2bf(u1.x); t[5] = (short)f2bf(u1.y);
      t[6] = (short)f2bf(u1.z); t[7] = (short)f2bf(u1.w);
      a[q] = t;
    }
  } else {
    const short8* Arow =
        (const short8*)((const unsigned short*)Aptr + (size_t)(r0 + (l & 15)) * 128 + ((l >> 4) << 3));
    #pragma unroll
    for (int q = 0; q < 4; ++q) a[q] = Arow[q * 4];
  }
  const short8* Wv = (const short8*)Wf + l;
  constexpr int NT = BNO / 16;
  float4v acc[NT];
  #pragma unroll
  for (int t = 0; t < NT; ++t) {
    acc[t] = (float4v){0.f, 0.f, 0.f, 0.f};
    #pragma unroll
    for (int q = 0; q < 4; ++q) {
      short8 b = Wv[(t * 4 + q) * 64];
      acc[t] = __builtin_amdgcn_mfma_f32_16x16x32_bf16(a[q], b, acc[t], 0, 0, 0);
    }
  }
  int orow = r0 + ((l >> 4) << 2);
  int ocol = l & 15;
  float dv[4];
  #pragma unroll
  for (int r = 0; r < 4; ++r) dv[r] = dinv[orow + r];
  #pragma unroll
  for (int t = 0; t < NT; ++t) {
    #pragma unroll
    for (int r = 0; r < 4; ++r) {
      float val = acc[t][r] * dv[r];
      if constexpr (OUT8) {
        unsigned int u = __builtin_amdgcn_cvt_pk_fp8_f32(val, val, 0u, false);
        ((unsigned char*)Cptr)[(size_t)(orow + r) * BNO + t * 16 + ocol] = (unsigned char)(u & 0xffu);
      } else {
        ((unsigned short*)Cptr)[(size_t)(orow + r) * BNO + t * 16 + ocol] = f2bf(val);
      }
    }
  }
}

// ---------------------------------------------------------------- aggregation (F=128, fp8 H')
// PAIR-NODE: each wave processes 2 nodes simultaneously -> 8 gather instrs /
// 32 edges in flight. Quarter-wave per edge (16 lanes x uint2 = 128B fp8 row).
__global__ __launch_bounds__(256) void aggregate128_k(
    const unsigned char* __restrict__ H8, const int* __restrict__ row_start,
    const int* __restrict__ deg, const int* __restrict__ csr_src,
    const float* __restrict__ dinv, const float* __restrict__ bias,
    unsigned int* __restrict__ outp, float* __restrict__ stats) {
  __shared__ float s_sum[128], s_sq[128];
  int tid = threadIdx.x;
  if (tid < 128) { s_sum[tid] = 0.f; s_sq[tid] = 0.f; }
  __syncthreads();
  int lane = tid & 63;
  int qt = lane >> 4;    // edge of the quad
  int ql = lane & 15;    // uint2 index in row (channels 8ql..8ql+7)
  int nwaves = gridDim.x * (blockDim.x >> 6);
  int gwave = (int)((blockIdx.x * blockDim.x + tid) >> 6);
  const uint2* H2 = (const uint2*)H8;  // 16 uint2 per row
  float4 blo = ((const float4*)bias)[2 * ql];
  float4 bhi = ((const float4*)bias)[2 * ql + 1];
  float st[8] = {0.f, 0.f, 0.f, 0.f, 0.f, 0.f, 0.f, 0.f};
  float sq[8] = {0.f, 0.f, 0.f, 0.f, 0.f, 0.f, 0.f, 0.f};
  auto accum = [](float (&a)[8], uint2 v) {
    float2v p0 = __builtin_amdgcn_cvt_pk_f32_fp8(v.x, false);
    float2v p1 = __builtin_amdgcn_cvt_pk_f32_fp8(v.x, true);
    float2v p2 = __builtin_amdgcn_cvt_pk_f32_fp8(v.y, false);
    float2v p3 = __builtin_amdgcn_cvt_pk_f32_fp8(v.y, true);
    a[0] += p0.x; a[1] += p0.y; a[2] += p1.x; a[3] += p1.y;
    a[4] += p2.x; a[5] += p2.y; a[6] += p3.x; a[7] += p3.y;
  };
  constexpr int kNP = kN / 2;
  for (int pr = gwave; pr < kNP; pr += nwaves) {
    int n0 = 2 * pr, n1 = 2 * pr + 1;
    int rs0 = row_start[n0], rs1 = row_start[n1];
    int pd0 = (deg[n0] + kPad - 1) & ~(kPad - 1);
    int pd1 = (deg[n1] + kPad - 1) & ~(kPad - 1);
    float di0 = dinv[n0], di1 = dinv[n1];
    float a0[8] = {0.f, 0.f, 0.f, 0.f, 0.f, 0.f, 0.f, 0.f};
    float a1[8] = {0.f, 0.f, 0.f, 0.f, 0.f, 0.f, 0.f, 0.f};
    int nb = ((pd0 > pd1 ? pd0 : pd1)) >> 4;
    for (int i = 0; i < nb; ++i) {
      bool ok0 = (i << 4) < pd0, ok1 = (i << 4) < pd1;
      int b0 = rs0 + (i << 4) + qt, b1 = rs1 + (i << 4) + qt;
      int s0[4], s1[4];
      uint2 v0[4], v1[4];
      #pragma unroll
      for (int j = 0; j < 4; ++j) s0[j] = ok0 ? csr_src[b0 + 4 * j] : kN;
      #pragma unroll
      for (int j = 0; j < 4; ++j) s1[j] = ok1 ? csr_src[b1 + 4 * j] : kN;
      #pragma unroll
      for (int j = 0; j < 4; ++j) v0[j] = H2[(size_t)s0[j] * 16 + ql];
      #pragma unroll
      for (int j = 0; j < 4; ++j) v1[j] = H2[(size_t)s1[j] * 16 + ql];
      #pragma unroll
      for (int j = 0; j < 4; ++j) { accum(a0, v0[j]); accum(a1, v1[j]); }
    }
    #pragma unroll
    for (int j = 0; j < 8; ++j) {
      a0[j] += __shfl_xor(a0[j], 16, 64);
      a0[j] += __shfl_xor(a0[j], 32, 64);
      a1[j] += __shfl_xor(a1[j], 16, 64);
      a1[j] += __shfl_xor(a1[j], 32, 64);
    }
    accum(a0, H2[(size_t)n0 * 16 + ql]);  // self terms, post-reduce
    accum(a1, H2[(size_t)n1 * 16 + ql]);
    float o0[8], o1[8];
    o0[0] = di0 * a0[0] + blo.x; o0[1] = di0 * a0[1] + blo.y;
    o0[2] = di0 * a0[2] + blo.z; o0[3] = di0 * a0[3] + blo.w;
    o0[4] = di0 * a0[4] + bhi.x; o0[5] = di0 * a0[5] + bhi.y;
    o0[6] = di0 * a0[6] + bhi.z; o0[7] = di0 * a0[7] + bhi.w;
    o1[0] = di1 * a1[0] + blo.x; o1[1] = di1 * a1[1] + blo.y;
    o1[2] = di1 * a1[2] + blo.z; o1[3] = di1 * a1[3] + blo.w;
    o1[4] = di1 * a1[4] + bhi.x; o1[5] = di1 * a1[5] + bhi.y;
    o1[6] = di1 * a1[6] + bhi.z; o1[7] = di1 * a1[7] + bhi.w;
    if (qt == 0) {
      uint4 ov0, ov1;
      ov0.x = pack2bf(o0[0], o0[1]); ov0.y = pack2bf(o0[2], o0[3]);
      ov0.z = pack2bf(o0[4], o0[5]); ov0.w = pack2bf(o0[6], o0[7]);
      ov1.x = pack2bf(o1[0], o1[1]); ov1.y = pack2bf(o1[2], o1[3]);
      ov1.z = pack2bf(o1[4], o1[5]); ov1.w = pack2bf(o1[6], o1[7]);
      ((uint4*)outp)[(size_t)n0 * 16 + ql] = ov0;
      ((uint4*)outp)[(size_t)n1 * 16 + ql] = ov1;
      #pragma unroll
      for (int j = 0; j < 8; ++j) {
        st[j] += o0[j] + o1[j];
        sq[j] += o0[j] * o0[j] + o1[j] * o1[j];
      }
    }
  }
  if (qt == 0) {
    #pragma unroll
    for (int j = 0; j < 8; ++j) {
      atomicAdd(&s_sum[8 * ql + j], st[j]);
      atomicAdd(&s_sq[8 * ql + j], sq[j]);
    }
  }
  __syncthreads();
  if (tid < 128) {
    atomicAdd(&stats[tid], s_sum[tid]);
    atomicAdd(&stats[128 + tid], s_sq[tid]);
  }
}

// ---------------------------------------------------------------- aggregation (F=64, final, bf16)
// PAIR-NODE, quarter-wave per edge: 8 gather instrs / 32 edges in flight.
__global__ __launch_bounds__(256) void aggregate64_k(
    const unsigned short* __restrict__ Hb, const int* __restrict__ row_start,
    const int* __restrict__ deg, const int* __restrict__ csr_src,
    const float* __restrict__ dinv, const float* __restrict__ bias,
    float* __restrict__ outp) {
  int tid = threadIdx.x;
  int lane = tid & 63;
  int qt = lane >> 4;
  int ql = lane & 15;
  int nwaves = gridDim.x * (blockDim.x >> 6);
  int gwave = (int)((blockIdx.x * blockDim.x + tid) >> 6);
  const uint2* H2 = (const uint2*)Hb;  // 16 uint2 per row (cols 4ql..4ql+3)
  float4 b4 = ((const float4*)bias)[ql];
  auto accum = [](float (&a)[4], uint2 v) {
    a[0] += bf2f(v.x & 0xffffu); a[1] += bf2f(v.x >> 16);
    a[2] += bf2f(v.y & 0xffffu); a[3] += bf2f(v.y >> 16);
  };
  constexpr int kNP = kN / 2;
  for (int pr = gwave; pr < kNP; pr += nwaves) {
    int n0 = 2 * pr, n1 = 2 * pr + 1;
    int rs0 = row_start[n0], rs1 = row_start[n1];
    int pd0 = (deg[n0] + kPad - 1) & ~(kPad - 1);
    int pd1 = (deg[n1] + kPad - 1) & ~(kPad - 1);
    float di0 = dinv[n0], di1 = dinv[n1];
    float a0[4] = {0.f, 0.f, 0.f, 0.f};
    float a1[4] = {0.f, 0.f, 0.f, 0.f};
    int nb = ((pd0 > pd1 ? pd0 : pd1)) >> 4;
    for (int i = 0; i < nb; ++i) {
      bool ok0 = (i << 4) < pd0, ok1 = (i << 4) < pd1;
      int b0 = rs0 + (i << 4) + qt, b1 = rs1 + (i << 4) + qt;
      int s0[4], s1[4];
      uint2 v0[4], v1[4];
      #pragma unroll
      for (int j = 0; j < 4; ++j) s0[j] = ok0 ? csr_src[b0 + 4 * j] : kN;
      #pragma unroll
      for (int j = 0; j < 4; ++j) s1[j] = ok1 ? csr_src[b1 + 4 * j] : kN;
      #pragma unroll
      for (int j = 0; j < 4; ++j) v0[j] = H2[(size_t)s0[j] * 16 + ql];
      #pragma unroll
      for (int j = 0; j < 4; ++j) v1[j] = H2[(size_t)s1[j] * 16 + ql];
      #pragma unroll
      for (int j = 0; j < 4; ++j) { accum(a0, v0[j]); accum(a1, v1[j]); }
    }
    #pragma unroll
    for (int j = 0; j < 4; ++j) {
      a0[j] += __shfl_xor(a0[j], 16, 64);
      a0[j] += __shfl_xor(a0[j], 32, 64);
      a1[j] += __shfl_xor(a1[j], 16, 64);
      a1[j] += __shfl_xor(a1[j], 32, 64);
    }
    accum(a0, H2[(size_t)n0 * 16 + ql]);
    accum(a1, H2[(size_t)n1 * 16 + ql]);
    if (qt == 0) {
      ((float4*)outp)[(size_t)n0 * 16 + ql] =
          make_float4(di0 * a0[0] + b4.x, di0 * a0[1] + b4.y,
                      di0 * a0[2] + b4.z, di0 * a0[3] + b4.w);
      ((float4*)outp)[(size_t)n1 * 16 + ql] =
          make_float4(di1 * a1[0] + b4.x, di1 * a1[1] + b4.y,
                      di1 * a1[2] + b4.z, di1 * a1[3] + b4.w);
    }
  }
}

// ---------------------------------------------------------------- BN apply (finalize fused)
// z = scale[c]*a + shift[c] + r; optional bf16 z store; always bf16(relu(z)).
template <bool WRITE_Z, bool RF32>
__global__ void bn_apply_res_k(const unsigned int* __restrict__ a, const void* __restrict__ rp,
                               const float* __restrict__ stats, const float* __restrict__ g,
                               const float* __restrict__ be, unsigned int* __restrict__ z,
                               unsigned int* __restrict__ rb) {
  __shared__ float lss[256];
  int t = threadIdx.x;
  if (t < 128) {
    float mean = stats[t] * (1.f / kN);
    float var = stats[128 + t] * (1.f / kN) - mean * mean;
    float inv = rsqrtf(var + kEps);
    float sc = g[t] * inv;
    lss[t] = sc;
    lss[128 + t] = be[t] - mean * sc;
  }
  __syncthreads();
  int idx = blockIdx.x * blockDim.x + t;  // kN*16 groups of 8 bf16
  if (idx >= kN * 16) return;
  uint4 av = ((const uint4*)a)[idx];
  float r[8];
  if constexpr (RF32) {
    float4 r0 = ((const float4*)rp)[idx * 2];
    float4 r1 = ((const float4*)rp)[idx * 2 + 1];
    r[0] = r0.x; r[1] = r0.y; r[2] = r0.z; r[3] = r0.w;
    r[4] = r1.x; r[5] = r1.y; r[6] = r1.z; r[7] = r1.w;
  } else {
    uint4 rv = ((const uint4*)rp)[idx];
    r[0] = bf2f(rv.x & 0xffffu); r[1] = bf2f(rv.x >> 16);
    r[2] = bf2f(rv.y & 0xffffu); r[3] = bf2f(rv.y >> 16);
    r[4] = bf2f(rv.z & 0xffffu); r[5] = bf2f(rv.z >> 16);
    r[6] = bf2f(rv.w & 0xffffu); r[7] = bf2f(rv.w >> 16);
  }
  int c = (idx & 15) * 8;
  float o[8];
  unsigned int apk[4] = {av.x, av.y, av.z, av.w};
  #pragma unroll
  for (int j = 0; j < 4; ++j) {
    o[2 * j]     = lss[c + 2 * j] * bf2f(apk[j] & 0xffffu) + lss[128 + c + 2 * j] + r[2 * j];
    o[2 * j + 1] = lss[c + 2 * j + 1] * bf2f(apk[j] >> 16) + lss[128 + c + 2 * j + 1] + r[2 * j + 1];
  }
  if (WRITE_Z) {
    uint4 zv;
    zv.x = pack2bf(o[0], o[1]); zv.y = pack2bf(o[2], o[3]);
    zv.z = pack2bf(o[4], o[5]); zv.w = pack2bf(o[6], o[7]);
    ((uint4*)z)[idx] = zv;
  }
  uint4 hv;
  hv.x = pack2bf(fmaxf(o[0], 0.f), fmaxf(o[1], 0.f));
  hv.y = pack2bf(fmaxf(o[2], 0.f), fmaxf(o[3], 0.f));
  hv.z = pack2bf(fmaxf(o[4], 0.f), fmaxf(o[5], 0.f));
  hv.w = pack2bf(fmaxf(o[6], 0.f), fmaxf(o[7], 0.f));
  ((uint4*)rb)[idx] = hv;
}

// ---------------------------------------------------------------- launch
extern "C" void kernel_launch(void* const* d_in, const int* in_sizes, int n_in,
                              void* d_out, int out_size, void* d_ws, size_t ws_size,
                              hipStream_t stream) {
  const float* x   = (const float*)d_in[0];
  const int*   ei  = (const int*)d_in[1];
  const float* W1  = (const float*)d_in[2];
  const float* b1  = (const float*)d_in[3];
  const float* g1  = (const float*)d_in[4];
  const float* be1 = (const float*)d_in[5];
  const float* W2  = (const float*)d_in[6];
  const float* b2  = (const float*)d_in[7];
  const float* g2  = (const float*)d_in[8];
  const float* be2 = (const float*)d_in[9];
  const float* W3  = (const float*)d_in[10];
  const float* b3  = (const float*)d_in[11];
  float* outp = (float*)d_out;

  const int* src = ei;
  const int* dst = ei + kE;

  char* ws = (char*)d_ws;
  size_t off = 0;
  auto alloc = [&](size_t bytes) -> void* {
    void* p = ws + off;
    off = (off + bytes + 255) & ~size_t(255);
    return p;
  };
  // +1 row on H' buffers: dummy zero row at index kN for degree padding.
  unsigned char* hF8 = (unsigned char*)alloc((size_t)(kN + 1) * 128);      // H' fp8 (layers 1-2)
  unsigned short* hH = (unsigned short*)alloc((size_t)(kN + 1) * 64 * 2);  // H' bf16 (layer 3)
  unsigned int* aB = (unsigned int*)alloc((size_t)kN * 64 * 4);       // agg out (packed bf16)
  unsigned int* zC = (unsigned int*)alloc((size_t)kN * 64 * 4);       // z1 residual (packed bf16)
  unsigned int* hb = (unsigned int*)alloc((size_t)kN * 64 * 4);       // relu out / gemm in
  int*   csr_src  = (int*)alloc((size_t)3200000 * 4);                 // padded CSR (<= E + 16N)
  int2*  gstage   = (int2*)alloc((size_t)kNB * kBCAP * 8);            // ~19.3 MB
  // deg and gcursor must stay adjacent: one memset covers both.
  int*   deg      = (int*)alloc((size_t)kN * 4);
  int*   gcursor  = (int*)alloc(kNB * 4);
  float* dinv     = (float*)alloc((size_t)kN * 4);
  int*   rowst    = (int*)alloc((size_t)kN * 4);
  float* stats    = (float*)alloc(256 * 4);
  int*   counter  = (int*)alloc(4);
  unsigned short* wf1 = (unsigned short*)alloc(128 * 128 * 2);
  unsigned short* wf2 = (unsigned short*)alloc(128 * 128 * 2);
  unsigned short* wf3 = (unsigned short*)alloc(128 * 64 * 2);

  const int TB = 256;
  int blkNn = (kN + TB - 1) / TB;
  int blkBin = (kE + kCHUNK - 1) / kCHUNK;  // 391
  int blkGemm = (kN / 16 + 3) / 4;
  int blkApply = kN * 16 / TB;      // 6250
  const int blkAgg = 2048;

  // CSR build: memset(deg+gcursor) -> bin -> padded scan -> bucket-local scatter+pad
  size_t degPad = (((size_t)kN * 4) + 255) & ~size_t(255);
  hipMemsetAsync(deg, 0, degPad + kNB * 4, stream);
  bin_k<<<blkBin, TB, 0, stream>>>(src, dst, deg, counter, gcursor, gstage);
  alloc_rows_k<<<blkNn, TB, 0, stream>>>(deg, rowst, counter, dinv);
  scatter2_k<<<kNB, TB, 0, stream>>>(gstage, gcursor, rowst, deg, csr_src);
  convert_w_all_k<<<21, TB, 0, stream>>>(W1, W2, W3, wf1, wf2, wf3, hF8, hH);

  // Layer 1 (A = fp32 x, residual = fp32 x); H' in fp8
  gemm_mfma_k<128, true, true><<<blkGemm, 256, 0, stream>>>(x, wf1, dinv, hF8, stats);
  aggregate128_k<<<blkAgg, TB, 0, stream>>>(hF8, rowst, deg, csr_src, dinv, b1, aB, stats);
  bn_apply_res_k<true, true><<<blkApply, TB, 0, stream>>>(aB, x, stats, g1, be1, zC, hb);

  // Layer 2 (residual = z1 bf16); H' in fp8
  gemm_mfma_k<128, false, true><<<blkGemm, 256, 0, stream>>>((const unsigned short*)hb, wf2, dinv, hF8, stats);
  aggregate128_k<<<blkAgg, TB, 0, stream>>>(hF8, rowst, deg, csr_src, dinv, b2, aB, stats);
  bn_apply_res_k<false, false><<<blkApply, TB, 0, stream>>>(aB, zC, stats, g2, be2, nullptr, hb);

  // Layer 3: H' in bf16 (final output path — keep precision)
  gemm_mfma_k<64, false, false><<<blkGemm, 256, 0, stream>>>((const unsigned short*)hb, wf3, dinv, hH, nullptr);
  aggregate64_k<<<blkAgg, TB, 0, stream>>>(hH, rowst, deg, csr_src, dinv, b3, outp);
}

// Round 12
// 491.417 us; speedup vs baseline: 1.1753x; 1.1753x over previous
//
#include <hip/hip_runtime.h>

static constexpr int kN = 100000;
static constexpr int kE = 1600000;
static constexpr float kEps = 1e-5f;

static constexpr int kBSH = 9;                          // 512 nodes per bucket
static constexpr int kNB = (kN + 511) >> kBSH;          // 196 buckets
static constexpr int kBCAP = 12288;                     // staging cap per bucket
static constexpr int kCHUNK = 4096;                     // edges per bin_k block
static constexpr int kPad = 16;                         // degree padding quantum

typedef __attribute__((ext_vector_type(8))) short short8;   // 8 bf16 = 4 VGPRs
typedef __attribute__((ext_vector_type(4))) float float4v;  // MFMA acc
typedef __attribute__((ext_vector_type(2))) float float2v;

static __device__ inline unsigned short f2bf(float f) {
  union { float f; unsigned int u; } v; v.f = f;
  unsigned int r = v.u + 0x7fffu + ((v.u >> 16) & 1u);  // RNE
  return (unsigned short)(r >> 16);
}
static __device__ inline float bf2f(unsigned int bits16) {
  union { unsigned int u; float f; } v; v.u = bits16 << 16; return v.f;
}
static __device__ inline unsigned int pack2bf(float lo, float hi) {
  return (unsigned int)f2bf(lo) | ((unsigned int)f2bf(hi) << 16);
}

// ---------------------------------------------------------------- binning (phase 1)
__global__ __launch_bounds__(256) void bin_k(const int* __restrict__ src,
                                             const int* __restrict__ dst,
                                             int* __restrict__ deg,
                                             int* __restrict__ counter,
                                             int* __restrict__ gcursor,
                                             int2* __restrict__ gstage) {
  __shared__ int s_cnt[256];
  __shared__ int s_scan[256];
  __shared__ int s_base[256];
  __shared__ int s_cur[256];
  __shared__ int s_gb[256];
  __shared__ int2 s_stage[kCHUNK];
  int tid = threadIdx.x;
  if (blockIdx.x == 0 && tid == 0) *counter = 0;
  int e0 = blockIdx.x * kCHUNK;
  int n = kE - e0; if (n > kCHUNK) n = kCHUNK;
  s_cnt[tid] = 0;
  __syncthreads();
  for (int j = tid; j < n; j += 256) {
    int d = dst[e0 + j];
    atomicAdd(&s_cnt[d >> kBSH], 1);
    atomicAdd(&deg[d], 1);
  }
  __syncthreads();
  int v = s_cnt[tid];
  s_scan[tid] = v;
  __syncthreads();
  #pragma unroll
  for (int o = 1; o < 256; o <<= 1) {
    int t = (tid >= o) ? s_scan[tid - o] : 0;
    __syncthreads();
    s_scan[tid] += t;
    __syncthreads();
  }
  int excl = s_scan[tid] - v;
  s_base[tid] = excl;
  s_cur[tid] = excl;
  __syncthreads();
  if (tid < kNB && s_cnt[tid] > 0) s_gb[tid] = atomicAdd(&gcursor[tid], s_cnt[tid]);
  for (int j = tid; j < n; j += 256) {
    int s = src[e0 + j];
    int d = dst[e0 + j];
    int p = atomicAdd(&s_cur[d >> kBSH], 1);
    s_stage[p] = make_int2(s, d);
  }
  __syncthreads();
  for (int j = tid; j < n; j += 256) {
    int2 e = s_stage[j];
    int b = e.y >> kBSH;
    gstage[(size_t)b * kBCAP + s_gb[b] + (j - s_base[b])] = e;
  }
}

// row starts via wave-scan bump allocation over PADDED degrees; also dinv.
__global__ void alloc_rows_k(const int* __restrict__ deg, int* __restrict__ row_start,
                             int* __restrict__ counter, float* __restrict__ dinv) {
  int i = blockIdx.x * blockDim.x + threadIdx.x;
  int lane = threadIdx.x & 63;
  int d = (i < kN) ? deg[i] : 0;
  int pd = (d + kPad - 1) & ~(kPad - 1);  // padded degree
  int x = pd;
  #pragma unroll
  for (int off = 1; off < 64; off <<= 1) {
    int y = __shfl_up(x, off, 64);
    if (lane >= off) x += y;
  }
  int total = __shfl(x, 63, 64);
  int base = 0;
  if (lane == 63) base = atomicAdd(counter, total);
  base = __shfl(base, 63, 64);
  int start = base + x - pd;
  if (i < kN) {
    row_start[i] = start;
    dinv[i] = rsqrtf((float)(d + 1));
  }
}

// ---------------------------------------------------------------- scatter (phase 2)
__global__ __launch_bounds__(256) void scatter2_k(const int2* __restrict__ gstage,
                                                  const int* __restrict__ gcursor,
                                                  const int* __restrict__ rowst,
                                                  const int* __restrict__ deg,
                                                  int* __restrict__ csr_src) {
  __shared__ int s_cur[1 << kBSH];
  int b = blockIdx.x, tid = threadIdx.x;
  int n0 = b << kBSH;
  int nn = kN - n0; if (nn > (1 << kBSH)) nn = 1 << kBSH;
  for (int i = tid; i < nn; i += 256) s_cur[i] = rowst[n0 + i];
  __syncthreads();
  int cnt = gcursor[b];
  const int2* seg = gstage + (size_t)b * kBCAP;
  for (int j = tid; j < cnt; j += 256) {
    int2 e = seg[j];
    int pos = atomicAdd(&s_cur[e.y - n0], 1);
    csr_src[pos] = e.x;
  }
  __syncthreads();
  // pad: fill [rowst+deg, rowst+pdeg) with dummy index kN
  for (int i = tid; i < nn; i += 256) {
    int d = deg[n0 + i];
    int endp = rowst[n0 + i] + ((d + kPad - 1) & ~(kPad - 1));
    for (int p = s_cur[i]; p < endp; ++p) csr_src[p] = kN;
  }
}

// ---------------------------------------------------------------- weight convert + dummy-row zero
__global__ void convert_w_all_k(const float* __restrict__ W1, const float* __restrict__ W2,
                                const float* __restrict__ W3,
                                unsigned short* __restrict__ wf1,
                                unsigned short* __restrict__ wf2,
                                unsigned short* __restrict__ wf3,
                                unsigned char* __restrict__ hF8,
                                unsigned short* __restrict__ hH) {
  int tid = blockIdx.x * blockDim.x + threadIdx.x;
  const float* W;
  unsigned short* Wf;
  int BNO;
  if (tid < 2048) { W = W1; Wf = wf1; BNO = 128; }
  else if (tid < 4096) { W = W2; Wf = wf2; BNO = 128; tid -= 2048; }
  else if (tid < 5120) { W = W3; Wf = wf3; BNO = 64; tid -= 4096; }
  else if (tid < 5152) {  // zero dummy fp8 row (128B = 32 uints)
    ((unsigned int*)(hF8 + (size_t)kN * 128))[tid - 5120] = 0u;
    return;
  } else if (tid < 5184) {  // zero dummy bf16 row (128B = 32 uints)
    ((unsigned int*)(hH + (size_t)kN * 64))[tid - 5152] = 0u;
    return;
  } else return;
  int l = tid & 63;
  int frag = tid >> 6;
  int q = frag & 3;
  int t = frag >> 2;
  int n = t * 16 + (l & 15);
  int kbase = q * 32 + ((l >> 4) << 3);
  unsigned short v[8] __attribute__((aligned(16)));
  #pragma unroll
  for (int j = 0; j < 8; ++j) v[j] = f2bf(W[(kbase + j) * BNO + n]);
  ((uint4*)Wf)[tid] = *(const uint4*)v;
}

// ---------------------------------------------------------------- MFMA GEMM -> H' out
template <int BNO, bool AF32, bool OUT8>
__global__ __launch_bounds__(256) void gemm_mfma_k(const void* __restrict__ Aptr,
                                                   const unsigned short* __restrict__ Wf,
                                                   const float* __restrict__ dinv,
                                                   void* __restrict__ Cptr,
                                                   float* __restrict__ stats) {
  if (stats && blockIdx.x == 0) stats[threadIdx.x] = 0.f;
  int wid = (int)((blockIdx.x * blockDim.x + threadIdx.x) >> 6);
  if (wid >= kN / 16) return;  // 100000 = 16 * 6250
  int l = threadIdx.x & 63;
  int r0 = wid * 16;
  short8 a[4];
  if constexpr (AF32) {
    const float* Af = (const float*)Aptr + (size_t)(r0 + (l & 15)) * 128 + ((l >> 4) << 3);
    #pragma unroll
    for (int q = 0; q < 4; ++q) {
      float4 u0 = *(const float4*)(Af + q * 32);
      float4 u1 = *(const float4*)(Af + q * 32 + 4);
      short8 t;
      t[0] = (short)f2bf(u0.x); t[1] = (short)f2bf(u0.y);
      t[2] = (short)f2bf(u0.z); t[3] = (short)f2bf(u0.w);
      t[4] = (short)f2bf(u1.x); t[5] = (short)f2bf(u1.y);
      t[6] = (short)f2bf(u1.z); t[7] = (short)f2bf(u1.w);
      a[q] = t;
    }
  } else {
    const short8* Arow =
        (const short8*)((const unsigned short*)Aptr + (size_t)(r0 + (l & 15)) * 128 + ((l >> 4) << 3));
    #pragma unroll
    for (int q = 0; q < 4; ++q) a[q] = Arow[q * 4];
  }
  const short8* Wv = (const short8*)Wf + l;
  constexpr int NT = BNO / 16;
  float4v acc[NT];
  #pragma unroll
  for (int t = 0; t < NT; ++t) {
    acc[t] = (float4v){0.f, 0.f, 0.f, 0.f};
    #pragma unroll
    for (int q = 0; q < 4; ++q) {
      short8 b = Wv[(t * 4 + q) * 64];
      acc[t] = __builtin_amdgcn_mfma_f32_16x16x32_bf16(a[q], b, acc[t], 0, 0, 0);
    }
  }
  int orow = r0 + ((l >> 4) << 2);
  int ocol = l & 15;
  float dv[4];
  #pragma unroll
  for (int r = 0; r < 4; ++r) dv[r] = dinv[orow + r];
  #pragma unroll
  for (int t = 0; t < NT; ++t) {
    #pragma unroll
    for (int r = 0; r < 4; ++r) {
      float val = acc[t][r] * dv[r];
      if constexpr (OUT8) {
        unsigned int u = __builtin_amdgcn_cvt_pk_fp8_f32(val, val, 0u, false);
        ((unsigned char*)Cptr)[(size_t)(orow + r) * BNO + t * 16 + ocol] = (unsigned char)(u & 0xffu);
      } else {
        ((unsigned short*)Cptr)[(size_t)(orow + r) * BNO + t * 16 + ocol] = f2bf(val);
      }
    }
  }
}

// ---------------------------------------------------------------- aggregation (F=128, fp8 H')
// Single node per wave; ONE coalesced csr load per node (lane l -> slot l,
// covers deg<=64); gather indices distributed via shfl (no per-block csr vmem).
// Next node's row_start/deg/dinv/csr prefetched during current node's gathers.
__global__ __launch_bounds__(256) void aggregate128_k(
    const unsigned char* __restrict__ H8, const int* __restrict__ row_start,
    const int* __restrict__ deg, const int* __restrict__ csr_src,
    const float* __restrict__ dinv, const float* __restrict__ bias,
    unsigned int* __restrict__ outp, float* __restrict__ stats) {
  __shared__ float s_sum[128], s_sq[128];
  int tid = threadIdx.x;
  if (tid < 128) { s_sum[tid] = 0.f; s_sq[tid] = 0.f; }
  __syncthreads();
  int lane = tid & 63;
  int qt = lane >> 4;    // edge of the quad
  int ql = lane & 15;    // uint2 index in row (channels 8ql..8ql+7)
  int nwaves = gridDim.x * (blockDim.x >> 6);
  int gwave = (int)((blockIdx.x * blockDim.x + tid) >> 6);
  const uint2* H2 = (const uint2*)H8;  // 16 uint2 per row
  float4 blo = ((const float4*)bias)[2 * ql];
  float4 bhi = ((const float4*)bias)[2 * ql + 1];
  float st[8] = {0.f, 0.f, 0.f, 0.f, 0.f, 0.f, 0.f, 0.f};
  float sqa[8] = {0.f, 0.f, 0.f, 0.f, 0.f, 0.f, 0.f, 0.f};
  auto accum = [](float (&a)[8], uint2 v) {
    float2v p0 = __builtin_amdgcn_cvt_pk_f32_fp8(v.x, false);
    float2v p1 = __builtin_amdgcn_cvt_pk_f32_fp8(v.x, true);
    float2v p2 = __builtin_amdgcn_cvt_pk_f32_fp8(v.y, false);
    float2v p3 = __builtin_amdgcn_cvt_pk_f32_fp8(v.y, true);
    a[0] += p0.x; a[1] += p0.y; a[2] += p1.x; a[3] += p1.y;
    a[4] += p2.x; a[5] += p2.y; a[6] += p3.x; a[7] += p3.y;
  };
  // prefetch first node
  int node = gwave;
  int rs = 0, pd = 0;
  float di = 1.f;
  int ec = kN;
  if (node < kN) {
    rs = row_start[node];
    pd = (deg[node] + kPad - 1) & ~(kPad - 1);
    di = dinv[node];
    ec = csr_src[rs + lane];  // one coalesced 64-slot load (csr padded +64)
  }
  while (node < kN) {
    int cur_rs = rs, cur_pd = pd, cur_e = ec;
    float cur_di = di;
    int nxt = node + nwaves;
    if (nxt < kN) {  // prefetch next node (overlaps current gathers/accum)
      rs = row_start[nxt];
      pd = (deg[nxt] + kPad - 1) & ~(kPad - 1);
      di = dinv[nxt];
      ec = csr_src[rs + lane];
    }
    float a[8] = {0.f, 0.f, 0.f, 0.f, 0.f, 0.f, 0.f, 0.f};
    uint2 vself = H2[(size_t)node * 16 + ql];  // independent, issue early
    int nb = cur_pd >> 4;
    int nb4 = nb > 4 ? 4 : nb;
    for (int i = 0; i < nb4; ++i) {
      int s[4];
      uint2 v[4];
      #pragma unroll
      for (int j = 0; j < 4; ++j) s[j] = __shfl(cur_e, i * 16 + 4 * j + qt, 64);
      #pragma unroll
      for (int j = 0; j < 4; ++j) v[j] = H2[(size_t)s[j] * 16 + ql];
      #pragma unroll
      for (int j = 0; j < 4; ++j) accum(a, v[j]);
    }
    for (int i = 4; i < nb; ++i) {  // rare deg > 64
      int ee = csr_src[cur_rs + i * 16 + (lane & 15)];
      int s[4];
      uint2 v[4];
      #pragma unroll
      for (int j = 0; j < 4; ++j) s[j] = __shfl(ee, 4 * j + qt, 64);
      #pragma unroll
      for (int j = 0; j < 4; ++j) v[j] = H2[(size_t)s[j] * 16 + ql];
      #pragma unroll
      for (int j = 0; j < 4; ++j) accum(a, v[j]);
    }
    #pragma unroll
    for (int j = 0; j < 8; ++j) {
      a[j] += __shfl_xor(a[j], 16, 64);
      a[j] += __shfl_xor(a[j], 32, 64);
    }
    accum(a, vself);  // self term, post-reduce (same on all quarters)
    float o[8];
    o[0] = cur_di * a[0] + blo.x; o[1] = cur_di * a[1] + blo.y;
    o[2] = cur_di * a[2] + blo.z; o[3] = cur_di * a[3] + blo.w;
    o[4] = cur_di * a[4] + bhi.x; o[5] = cur_di * a[5] + bhi.y;
    o[6] = cur_di * a[6] + bhi.z; o[7] = cur_di * a[7] + bhi.w;
    if (qt == 0) {
      uint4 ov;
      ov.x = pack2bf(o[0], o[1]); ov.y = pack2bf(o[2], o[3]);
      ov.z = pack2bf(o[4], o[5]); ov.w = pack2bf(o[6], o[7]);
      ((uint4*)outp)[(size_t)node * 16 + ql] = ov;
      #pragma unroll
      for (int j = 0; j < 8; ++j) { st[j] += o[j]; sqa[j] += o[j] * o[j]; }
    }
    node = nxt;
  }
  if (qt == 0) {
    #pragma unroll
    for (int j = 0; j < 8; ++j) {
      atomicAdd(&s_sum[8 * ql + j], st[j]);
      atomicAdd(&s_sq[8 * ql + j], sqa[j]);
    }
  }
  __syncthreads();
  if (tid < 128) {
    atomicAdd(&stats[tid], s_sum[tid]);
    atomicAdd(&stats[128 + tid], s_sq[tid]);
  }
}

// ---------------------------------------------------------------- aggregation (F=64, final, bf16)
// Same prefetch+shuffle structure; quarter-wave per edge (16 lanes x uint2).
__global__ __launch_bounds__(256) void aggregate64_k(
    const unsigned short* __restrict__ Hb, const int* __restrict__ row_start,
    const int* __restrict__ deg, const int* __restrict__ csr_src,
    const float* __restrict__ dinv, const float* __restrict__ bias,
    float* __restrict__ outp) {
  int tid = threadIdx.x;
  int lane = tid & 63;
  int qt = lane >> 4;
  int ql = lane & 15;
  int nwaves = gridDim.x * (blockDim.x >> 6);
  int gwave = (int)((blockIdx.x * blockDim.x + tid) >> 6);
  const uint2* H2 = (const uint2*)Hb;  // 16 uint2 per row (cols 4ql..4ql+3)
  float4 b4 = ((const float4*)bias)[ql];
  auto accum = [](float (&a)[4], uint2 v) {
    a[0] += bf2f(v.x & 0xffffu); a[1] += bf2f(v.x >> 16);
    a[2] += bf2f(v.y & 0xffffu); a[3] += bf2f(v.y >> 16);
  };
  int node = gwave;
  int rs = 0, pd = 0;
  float di = 1.f;
  int ec = kN;
  if (node < kN) {
    rs = row_start[node];
    pd = (deg[node] + kPad - 1) & ~(kPad - 1);
    di = dinv[node];
    ec = csr_src[rs + lane];
  }
  while (node < kN) {
    int cur_rs = rs, cur_pd = pd, cur_e = ec;
    float cur_di = di;
    int nxt = node + nwaves;
    if (nxt < kN) {
      rs = row_start[nxt];
      pd = (deg[nxt] + kPad - 1) & ~(kPad - 1);
      di = dinv[nxt];
      ec = csr_src[rs + lane];
    }
    float a[4] = {0.f, 0.f, 0.f, 0.f};
    uint2 vself = H2[(size_t)node * 16 + ql];
    int nb = cur_pd >> 4;
    int nb4 = nb > 4 ? 4 : nb;
    for (int i = 0; i < nb4; ++i) {
      int s[4];
      uint2 v[4];
      #pragma unroll
      for (int j = 0; j < 4; ++j) s[j] = __shfl(cur_e, i * 16 + 4 * j + qt, 64);
      #pragma unroll
      for (int j = 0; j < 4; ++j) v[j] = H2[(size_t)s[j] * 16 + ql];
      #pragma unroll
      for (int j = 0; j < 4; ++j) accum(a, v[j]);
    }
    for (int i = 4; i < nb; ++i) {
      int ee = csr_src[cur_rs + i * 16 + (lane & 15)];
      int s[4];
      uint2 v[4];
      #pragma unroll
      for (int j = 0; j < 4; ++j) s[j] = __shfl(ee, 4 * j + qt, 64);
      #pragma unroll
      for (int j = 0; j < 4; ++j) v[j] = H2[(size_t)s[j] * 16 + ql];
      #pragma unroll
      for (int j = 0; j < 4; ++j) accum(a, v[j]);
    }
    #pragma unroll
    for (int j = 0; j < 4; ++j) {
      a[j] += __shfl_xor(a[j], 16, 64);
      a[j] += __shfl_xor(a[j], 32, 64);
    }
    accum(a, vself);
    if (qt == 0) {
      ((float4*)outp)[(size_t)node * 16 + ql] =
          make_float4(cur_di * a[0] + b4.x, cur_di * a[1] + b4.y,
                      cur_di * a[2] + b4.z, cur_di * a[3] + b4.w);
    }
    node = nxt;
  }
}

// ---------------------------------------------------------------- BN apply (finalize fused)
template <bool WRITE_Z, bool RF32>
__global__ void bn_apply_res_k(const unsigned int* __restrict__ a, const void* __restrict__ rp,
                               const float* __restrict__ stats, const float* __restrict__ g,
                               const float* __restrict__ be, unsigned int* __restrict__ z,
                               unsigned int* __restrict__ rb) {
  __shared__ float lss[256];
  int t = threadIdx.x;
  if (t < 128) {
    float mean = stats[t] * (1.f / kN);
    float var = stats[128 + t] * (1.f / kN) - mean * mean;
    float inv = rsqrtf(var + kEps);
    float sc = g[t] * inv;
    lss[t] = sc;
    lss[128 + t] = be[t] - mean * sc;
  }
  __syncthreads();
  int idx = blockIdx.x * blockDim.x + t;  // kN*16 groups of 8 bf16
  if (idx >= kN * 16) return;
  uint4 av = ((const uint4*)a)[idx];
  float r[8];
  if constexpr (RF32) {
    float4 r0 = ((const float4*)rp)[idx * 2];
    float4 r1 = ((const float4*)rp)[idx * 2 + 1];
    r[0] = r0.x; r[1] = r0.y; r[2] = r0.z; r[3] = r0.w;
    r[4] = r1.x; r[5] = r1.y; r[6] = r1.z; r[7] = r1.w;
  } else {
    uint4 rv = ((const uint4*)rp)[idx];
    r[0] = bf2f(rv.x & 0xffffu); r[1] = bf2f(rv.x >> 16);
    r[2] = bf2f(rv.y & 0xffffu); r[3] = bf2f(rv.y >> 16);
    r[4] = bf2f(rv.z & 0xffffu); r[5] = bf2f(rv.z >> 16);
    r[6] = bf2f(rv.w & 0xffffu); r[7] = bf2f(rv.w >> 16);
  }
  int c = (idx & 15) * 8;
  float o[8];
  unsigned int apk[4] = {av.x, av.y, av.z, av.w};
  #pragma unroll
  for (int j = 0; j < 4; ++j) {
    o[2 * j]     = lss[c + 2 * j] * bf2f(apk[j] & 0xffffu) + lss[128 + c + 2 * j] + r[2 * j];
    o[2 * j + 1] = lss[c + 2 * j + 1] * bf2f(apk[j] >> 16) + lss[128 + c + 2 * j + 1] + r[2 * j + 1];
  }
  if (WRITE_Z) {
    uint4 zv;
    zv.x = pack2bf(o[0], o[1]); zv.y = pack2bf(o[2], o[3]);
    zv.z = pack2bf(o[4], o[5]); zv.w = pack2bf(o[6], o[7]);
    ((uint4*)z)[idx] = zv;
  }
  uint4 hv;
  hv.x = pack2bf(fmaxf(o[0], 0.f), fmaxf(o[1], 0.f));
  hv.y = pack2bf(fmaxf(o[2], 0.f), fmaxf(o[3], 0.f));
  hv.z = pack2bf(fmaxf(o[4], 0.f), fmaxf(o[5], 0.f));
  hv.w = pack2bf(fmaxf(o[6], 0.f), fmaxf(o[7], 0.f));
  ((uint4*)rb)[idx] = hv;
}

// ---------------------------------------------------------------- launch
extern "C" void kernel_launch(void* const* d_in, const int* in_sizes, int n_in,
                              void* d_out, int out_size, void* d_ws, size_t ws_size,
                              hipStream_t stream) {
  const float* x   = (const float*)d_in[0];
  const int*   ei  = (const int*)d_in[1];
  const float* W1  = (const float*)d_in[2];
  const float* b1  = (const float*)d_in[3];
  const float* g1  = (const float*)d_in[4];
  const float* be1 = (const float*)d_in[5];
  const float* W2  = (const float*)d_in[6];
  const float* b2  = (const float*)d_in[7];
  const float* g2  = (const float*)d_in[8];
  const float* be2 = (const float*)d_in[9];
  const float* W3  = (const float*)d_in[10];
  const float* b3  = (const float*)d_in[11];
  float* outp = (float*)d_out;

  const int* src = ei;
  const int* dst = ei + kE;

  char* ws = (char*)d_ws;
  size_t off = 0;
  auto alloc = [&](size_t bytes) -> void* {
    void* p = ws + off;
    off = (off + bytes + 255) & ~size_t(255);
    return p;
  };
  // +1 row on H' buffers: dummy zero row at index kN for degree padding.
  unsigned char* hF8 = (unsigned char*)alloc((size_t)(kN + 1) * 128);      // H' fp8 (layers 1-2)
  unsigned short* hH = (unsigned short*)alloc((size_t)(kN + 1) * 64 * 2);  // H' bf16 (layer 3)
  unsigned int* aB = (unsigned int*)alloc((size_t)kN * 64 * 4);       // agg out (packed bf16)
  unsigned int* zC = (unsigned int*)alloc((size_t)kN * 64 * 4);       // z1 residual (packed bf16)
  unsigned int* hb = (unsigned int*)alloc((size_t)kN * 64 * 4);       // relu out / gemm in
  int*   csr_src  = (int*)alloc((size_t)(3200000 + 64) * 4);          // padded CSR + 64-slot overread guard
  int2*  gstage   = (int2*)alloc((size_t)kNB * kBCAP * 8);            // ~19.3 MB
  // deg and gcursor must stay adjacent: one memset covers both.
  int*   deg      = (int*)alloc((size_t)kN * 4);
  int*   gcursor  = (int*)alloc(kNB * 4);
  float* dinv     = (float*)alloc((size_t)kN * 4);
  int*   rowst    = (int*)alloc((size_t)kN * 4);
  float* stats    = (float*)alloc(256 * 4);
  int*   counter  = (int*)alloc(4);
  unsigned short* wf1 = (unsigned short*)alloc(128 * 128 * 2);
  unsigned short* wf2 = (unsigned short*)alloc(128 * 128 * 2);
  unsigned short* wf3 = (unsigned short*)alloc(128 * 64 * 2);

  const int TB = 256;
  int blkNn = (kN + TB - 1) / TB;
  int blkBin = (kE + kCHUNK - 1) / kCHUNK;  // 391
  int blkGemm = (kN / 16 + 3) / 4;
  int blkApply = kN * 16 / TB;      // 6250
  const int blkAgg = 2048;

  // CSR build: memset(deg+gcursor) -> bin -> padded scan -> bucket-local scatter+pad
  size_t degPad = (((size_t)kN * 4) + 255) & ~size_t(255);
  hipMemsetAsync(deg, 0, degPad + kNB * 4, stream);
  bin_k<<<blkBin, TB, 0, stream>>>(src, dst, deg, counter, gcursor, gstage);
  alloc_rows_k<<<blkNn, TB, 0, stream>>>(deg, rowst, counter, dinv);
  scatter2_k<<<kNB, TB, 0, stream>>>(gstage, gcursor, rowst, deg, csr_src);
  convert_w_all_k<<<21, TB, 0, stream>>>(W1, W2, W3, wf1, wf2, wf3, hF8, hH);

  // Layer 1 (A = fp32 x, residual = fp32 x); H' in fp8
  gemm_mfma_k<128, true, true><<<blkGemm, 256, 0, stream>>>(x, wf1, dinv, hF8, stats);
  aggregate128_k<<<blkAgg, TB, 0, stream>>>(hF8, rowst, deg, csr_src, dinv, b1, aB, stats);
  bn_apply_res_k<true, true><<<blkApply, TB, 0, stream>>>(aB, x, stats, g1, be1, zC, hb);

  // Layer 2 (residual = z1 bf16); H' in fp8
  gemm_mfma_k<128, false, true><<<blkGemm, 256, 0, stream>>>((const unsigned short*)hb, wf2, dinv, hF8, stats);
  aggregate128_k<<<blkAgg, TB, 0, stream>>>(hF8, rowst, deg, csr_src, dinv, b2, aB, stats);
  bn_apply_res_k<false, false><<<blkApply, TB, 0, stream>>>(aB, zC, stats, g2, be2, nullptr, hb);

  // Layer 3: H' in bf16 (final output path — keep precision)
  gemm_mfma_k<64, false, false><<<blkGemm, 256, 0, stream>>>((const unsigned short*)hb, wf3, dinv, hH, nullptr);
  aggregate64_k<<<blkAgg, TB, 0, stream>>>(hH, rowst, deg, csr_src, dinv, b3, outp);
}

// Round 13
// 421.159 us; speedup vs baseline: 1.3714x; 1.1668x over previous
//
#include <hip/hip_runtime.h>

static constexpr int kN = 100000;
static constexpr int kE = 1600000;
static constexpr float kEps = 1e-5f;

static constexpr int kBSH = 9;                          // 512 nodes per bucket
static constexpr int kNB = (kN + 511) >> kBSH;          // 196 buckets
static constexpr int kBCAP = 12288;                     // staging cap per bucket
static constexpr int kCHUNK = 4096;                     // edges per bin_k block
static constexpr int kPad = 16;                         // degree padding quantum

typedef __attribute__((ext_vector_type(8))) short short8;   // 8 bf16 = 4 VGPRs
typedef __attribute__((ext_vector_type(4))) float float4v;  // MFMA acc
typedef __attribute__((ext_vector_type(2))) float float2v;

static __device__ inline unsigned short f2bf(float f) {
  union { float f; unsigned int u; } v; v.f = f;
  unsigned int r = v.u + 0x7fffu + ((v.u >> 16) & 1u);  // RNE
  return (unsigned short)(r >> 16);
}
static __device__ inline float bf2f(unsigned int bits16) {
  union { unsigned int u; float f; } v; v.u = bits16 << 16; return v.f;
}
static __device__ inline unsigned int pack2bf(float lo, float hi) {
  return (unsigned int)f2bf(lo) | ((unsigned int)f2bf(hi) << 16);
}

// ---------------------------------------------------------------- binning (phase 1)
// 512 threads/block for occupancy; NO deg atomics (deg comes from alloc_hist_k).
__global__ __launch_bounds__(512) void bin_k(const int* __restrict__ src,
                                             const int* __restrict__ dst,
                                             int* __restrict__ gcursor,
                                             int2* __restrict__ gstage) {
  __shared__ int s_cnt[256];
  __shared__ int s_scan[256];
  __shared__ int s_base[256];
  __shared__ int s_cur[256];
  __shared__ int s_gb[256];
  __shared__ int2 s_stage[kCHUNK];
  int tid = threadIdx.x;
  int e0 = blockIdx.x * kCHUNK;
  int n = kE - e0; if (n > kCHUNK) n = kCHUNK;
  if (tid < 256) s_cnt[tid] = 0;
  __syncthreads();
  for (int j = tid; j < n; j += 512) {
    atomicAdd(&s_cnt[dst[e0 + j] >> kBSH], 1);
  }
  __syncthreads();
  int v = 0;
  if (tid < 256) { v = s_cnt[tid]; s_scan[tid] = v; }
  __syncthreads();
  #pragma unroll
  for (int o = 1; o < 256; o <<= 1) {
    int t = (tid >= o && tid < 256) ? s_scan[tid - o] : 0;
    __syncthreads();
    if (tid < 256) s_scan[tid] += t;
    __syncthreads();
  }
  if (tid < 256) {
    int excl = s_scan[tid] - v;
    s_base[tid] = excl;
    s_cur[tid] = excl;
  }
  __syncthreads();
  if (tid < kNB && s_cnt[tid] > 0) s_gb[tid] = atomicAdd(&gcursor[tid], s_cnt[tid]);
  for (int j = tid; j < n; j += 512) {
    int s = src[e0 + j];
    int d = dst[e0 + j];
    int p = atomicAdd(&s_cur[d >> kBSH], 1);
    s_stage[p] = make_int2(s, d);
  }
  __syncthreads();
  for (int j = tid; j < n; j += 512) {
    int2 e = s_stage[j];
    int b = e.y >> kBSH;
    gstage[(size_t)b * kBCAP + s_gb[b] + (j - s_base[b])] = e;
  }
}

// ---------------------------------------------------------------- hist + alloc (fused)
// One block per bucket: LDS-histogram the bucket's staged edges -> deg; padded
// scan -> rowst (one global atomic per block); dinv. All writes coalesced.
__global__ __launch_bounds__(256) void alloc_hist_k(const int2* __restrict__ gstage,
                                                    const int* __restrict__ gcursor,
                                                    int* __restrict__ counter,
                                                    int* __restrict__ deg,
                                                    int* __restrict__ row_start,
                                                    float* __restrict__ dinv) {
  __shared__ int s_deg[1 << kBSH];
  __shared__ int s_scan[256];
  __shared__ int s_bcast;
  int b = blockIdx.x, tid = threadIdx.x;
  int n0 = b << kBSH;
  s_deg[tid] = 0;
  s_deg[tid + 256] = 0;
  __syncthreads();
  int cnt = gcursor[b];
  const int2* seg = gstage + (size_t)b * kBCAP;
  for (int j = tid; j < cnt; j += 256) {
    atomicAdd(&s_deg[seg[j].y - n0], 1);
  }
  __syncthreads();
  int i0 = 2 * tid, i1 = 2 * tid + 1;
  int d0 = s_deg[i0], d1 = s_deg[i1];
  int pd0 = (d0 + kPad - 1) & ~(kPad - 1);
  int pd1 = (d1 + kPad - 1) & ~(kPad - 1);
  int sum = pd0 + pd1;
  s_scan[tid] = sum;
  __syncthreads();
  #pragma unroll
  for (int o = 1; o < 256; o <<= 1) {
    int t = (tid >= o) ? s_scan[tid - o] : 0;
    __syncthreads();
    s_scan[tid] += t;
    __syncthreads();
  }
  if (tid == 255) s_bcast = atomicAdd(counter, s_scan[255]);
  __syncthreads();
  int base = s_bcast + s_scan[tid] - sum;
  int node0 = n0 + i0, node1 = n0 + i1;
  if (node0 < kN) {
    deg[node0] = d0;
    row_start[node0] = base;
    dinv[node0] = rsqrtf((float)(d0 + 1));
  }
  if (node1 < kN) {
    deg[node1] = d1;
    row_start[node1] = base + pd0;
    dinv[node1] = rsqrtf((float)(d1 + 1));
  }
}

// ---------------------------------------------------------------- scatter (phase 2)
__global__ __launch_bounds__(256) void scatter2_k(const int2* __restrict__ gstage,
                                                  const int* __restrict__ gcursor,
                                                  const int* __restrict__ rowst,
                                                  const int* __restrict__ deg,
                                                  int* __restrict__ csr_src) {
  __shared__ int s_cur[1 << kBSH];
  int b = blockIdx.x, tid = threadIdx.x;
  int n0 = b << kBSH;
  int nn = kN - n0; if (nn > (1 << kBSH)) nn = 1 << kBSH;
  for (int i = tid; i < nn; i += 256) s_cur[i] = rowst[n0 + i];
  __syncthreads();
  int cnt = gcursor[b];
  const int2* seg = gstage + (size_t)b * kBCAP;
  for (int j = tid; j < cnt; j += 256) {
    int2 e = seg[j];
    int pos = atomicAdd(&s_cur[e.y - n0], 1);
    csr_src[pos] = e.x;
  }
  __syncthreads();
  // pad: fill [rowst+deg, rowst+pdeg) with dummy index kN
  for (int i = tid; i < nn; i += 256) {
    int d = deg[n0 + i];
    int endp = rowst[n0 + i] + ((d + kPad - 1) & ~(kPad - 1));
    for (int p = s_cur[i]; p < endp; ++p) csr_src[p] = kN;
  }
}

// ---------------------------------------------------------------- weight convert + dummy-row zero
__global__ void convert_w_all_k(const float* __restrict__ W1, const float* __restrict__ W2,
                                const float* __restrict__ W3,
                                unsigned short* __restrict__ wf1,
                                unsigned short* __restrict__ wf2,
                                unsigned short* __restrict__ wf3,
                                unsigned char* __restrict__ hF8,
                                unsigned short* __restrict__ hH) {
  int tid = blockIdx.x * blockDim.x + threadIdx.x;
  const float* W;
  unsigned short* Wf;
  int BNO;
  if (tid < 2048) { W = W1; Wf = wf1; BNO = 128; }
  else if (tid < 4096) { W = W2; Wf = wf2; BNO = 128; tid -= 2048; }
  else if (tid < 5120) { W = W3; Wf = wf3; BNO = 64; tid -= 4096; }
  else if (tid < 5152) {  // zero dummy fp8 row (128B = 32 uints)
    ((unsigned int*)(hF8 + (size_t)kN * 128))[tid - 5120] = 0u;
    return;
  } else if (tid < 5184) {  // zero dummy bf16 row (128B = 32 uints)
    ((unsigned int*)(hH + (size_t)kN * 64))[tid - 5152] = 0u;
    return;
  } else return;
  int l = tid & 63;
  int frag = tid >> 6;
  int q = frag & 3;
  int t = frag >> 2;
  int n = t * 16 + (l & 15);
  int kbase = q * 32 + ((l >> 4) << 3);
  unsigned short v[8] __attribute__((aligned(16)));
  #pragma unroll
  for (int j = 0; j < 8; ++j) v[j] = f2bf(W[(kbase + j) * BNO + n]);
  ((uint4*)Wf)[tid] = *(const uint4*)v;
}

// ---------------------------------------------------------------- MFMA GEMM -> H' out
template <int BNO, bool AF32, bool OUT8>
__global__ __launch_bounds__(256) void gemm_mfma_k(const void* __restrict__ Aptr,
                                                   const unsigned short* __restrict__ Wf,
                                                   const float* __restrict__ dinv,
                                                   void* __restrict__ Cptr,
                                                   float* __restrict__ stats) {
  if (stats && blockIdx.x == 0) stats[threadIdx.x] = 0.f;
  int wid = (int)((blockIdx.x * blockDim.x + threadIdx.x) >> 6);
  if (wid >= kN / 16) return;  // 100000 = 16 * 6250
  int l = threadIdx.x & 63;
  int r0 = wid * 16;
  short8 a[4];
  if constexpr (AF32) {
    const float* Af = (const float*)Aptr + (size_t)(r0 + (l & 15)) * 128 + ((l >> 4) << 3);
    #pragma unroll
    for (int q = 0; q < 4; ++q) {
      float4 u0 = *(const float4*)(Af + q * 32);
      float4 u1 = *(const float4*)(Af + q * 32 + 4);
      short8 t;
      t[0] = (short)f2bf(u0.x); t[1] = (short)f2bf(u0.y);
      t[2] = (short)f2bf(u0.z); t[3] = (short)f2bf(u0.w);
      t[4] = (short)f2bf(u1.x); t[5] = (short)f2bf(u1.y);
      t[6] = (short)f2bf(u1.z); t[7] = (short)f2bf(u1.w);
      a[q] = t;
    }
  } else {
    const short8* Arow =
        (const short8*)((const unsigned short*)Aptr + (size_t)(r0 + (l & 15)) * 128 + ((l >> 4) << 3));
    #pragma unroll
    for (int q = 0; q < 4; ++q) a[q] = Arow[q * 4];
  }
  const short8* Wv = (const short8*)Wf + l;
  constexpr int NT = BNO / 16;
  float4v acc[NT];
  #pragma unroll
  for (int t = 0; t < NT; ++t) {
    acc[t] = (float4v){0.f, 0.f, 0.f, 0.f};
    #pragma unroll
    for (int q = 0; q < 4; ++q) {
      short8 b = Wv[(t * 4 + q) * 64];
      acc[t] = __builtin_amdgcn_mfma_f32_16x16x32_bf16(a[q], b, acc[t], 0, 0, 0);
    }
  }
  int orow = r0 + ((l >> 4) << 2);
  int ocol = l & 15;
  float dv[4];
  #pragma unroll
  for (int r = 0; r < 4; ++r) dv[r] = dinv[orow + r];
  #pragma unroll
  for (int t = 0; t < NT; ++t) {
    #pragma unroll
    for (int r = 0; r < 4; ++r) {
      float val = acc[t][r] * dv[r];
      if constexpr (OUT8) {
        unsigned int u = __builtin_amdgcn_cvt_pk_fp8_f32(val, val, 0u, false);
        ((unsigned char*)Cptr)[(size_t)(orow + r) * BNO + t * 16 + ocol] = (unsigned char)(u & 0xffu);
      } else {
        ((unsigned short*)Cptr)[(size_t)(orow + r) * BNO + t * 16 + ocol] = f2bf(val);
      }
    }
  }
}

// ---------------------------------------------------------------- aggregation (F=128, fp8 H')
// Single node per wave; ONE coalesced csr load per node (lane l -> slot l,
// covers deg<=64); gather indices distributed via shfl; next node prefetched.
__global__ __launch_bounds__(256) void aggregate128_k(
    const unsigned char* __restrict__ H8, const int* __restrict__ row_start,
    const int* __restrict__ deg, const int* __restrict__ csr_src,
    const float* __restrict__ dinv, const float* __restrict__ bias,
    unsigned int* __restrict__ outp, float* __restrict__ stats) {
  __shared__ float s_sum[128], s_sq[128];
  int tid = threadIdx.x;
  if (tid < 128) { s_sum[tid] = 0.f; s_sq[tid] = 0.f; }
  __syncthreads();
  int lane = tid & 63;
  int qt = lane >> 4;    // edge of the quad
  int ql = lane & 15;    // uint2 index in row (channels 8ql..8ql+7)
  int nwaves = gridDim.x * (blockDim.x >> 6);
  int gwave = (int)((blockIdx.x * blockDim.x + tid) >> 6);
  const uint2* H2 = (const uint2*)H8;  // 16 uint2 per row
  float4 blo = ((const float4*)bias)[2 * ql];
  float4 bhi = ((const float4*)bias)[2 * ql + 1];
  float st[8] = {0.f, 0.f, 0.f, 0.f, 0.f, 0.f, 0.f, 0.f};
  float sqa[8] = {0.f, 0.f, 0.f, 0.f, 0.f, 0.f, 0.f, 0.f};
  auto accum = [](float (&a)[8], uint2 v) {
    float2v p0 = __builtin_amdgcn_cvt_pk_f32_fp8(v.x, false);
    float2v p1 = __builtin_amdgcn_cvt_pk_f32_fp8(v.x, true);
    float2v p2 = __builtin_amdgcn_cvt_pk_f32_fp8(v.y, false);
    float2v p3 = __builtin_amdgcn_cvt_pk_f32_fp8(v.y, true);
    a[0] += p0.x; a[1] += p0.y; a[2] += p1.x; a[3] += p1.y;
    a[4] += p2.x; a[5] += p2.y; a[6] += p3.x; a[7] += p3.y;
  };
  // prefetch first node
  int node = gwave;
  int rs = 0, pd = 0;
  float di = 1.f;
  int ec = kN;
  if (node < kN) {
    rs = row_start[node];
    pd = (deg[node] + kPad - 1) & ~(kPad - 1);
    di = dinv[node];
    ec = csr_src[rs + lane];  // one coalesced 64-slot load (csr padded +64)
  }
  while (node < kN) {
    int cur_rs = rs, cur_pd = pd, cur_e = ec;
    float cur_di = di;
    int nxt = node + nwaves;
    if (nxt < kN) {  // prefetch next node (overlaps current gathers/accum)
      rs = row_start[nxt];
      pd = (deg[nxt] + kPad - 1) & ~(kPad - 1);
      di = dinv[nxt];
      ec = csr_src[rs + lane];
    }
    float a[8] = {0.f, 0.f, 0.f, 0.f, 0.f, 0.f, 0.f, 0.f};
    uint2 vself = H2[(size_t)node * 16 + ql];  // independent, issue early
    int nb = cur_pd >> 4;
    int nb4 = nb > 4 ? 4 : nb;
    for (int i = 0; i < nb4; ++i) {
      int s[4];
      uint2 v[4];
      #pragma unroll
      for (int j = 0; j < 4; ++j) s[j] = __shfl(cur_e, i * 16 + 4 * j + qt, 64);
      #pragma unroll
      for (int j = 0; j < 4; ++j) v[j] = H2[(size_t)s[j] * 16 + ql];
      #pragma unroll
      for (int j = 0; j < 4; ++j) accum(a, v[j]);
    }
    for (int i = 4; i < nb; ++i) {  // rare deg > 64
      int ee = csr_src[cur_rs + i * 16 + (lane & 15)];
      int s[4];
      uint2 v[4];
      #pragma unroll
      for (int j = 0; j < 4; ++j) s[j] = __shfl(ee, 4 * j + qt, 64);
      #pragma unroll
      for (int j = 0; j < 4; ++j) v[j] = H2[(size_t)s[j] * 16 + ql];
      #pragma unroll
      for (int j = 0; j < 4; ++j) accum(a, v[j]);
    }
    #pragma unroll
    for (int j = 0; j < 8; ++j) {
      a[j] += __shfl_xor(a[j], 16, 64);
      a[j] += __shfl_xor(a[j], 32, 64);
    }
    accum(a, vself);  // self term, post-reduce (same on all quarters)
    float o[8];
    o[0] = cur_di * a[0] + blo.x; o[1] = cur_di * a[1] + blo.y;
    o[2] = cur_di * a[2] + blo.z; o[3] = cur_di * a[3] + blo.w;
    o[4] = cur_di * a[4] + bhi.x; o[5] = cur_di * a[5] + bhi.y;
    o[6] = cur_di * a[6] + bhi.z; o[7] = cur_di * a[7] + bhi.w;
    if (qt == 0) {
      uint4 ov;
      ov.x = pack2bf(o[0], o[1]); ov.y = pack2bf(o[2], o[3]);
      ov.z = pack2bf(o[4], o[5]); ov.w = pack2bf(o[6], o[7]);
      ((uint4*)outp)[(size_t)node * 16 + ql] = ov;
      #pragma unroll
      for (int j = 0; j < 8; ++j) { st[j] += o[j]; sqa[j] += o[j] * o[j]; }
    }
    node = nxt;
  }
  if (qt == 0) {
    #pragma unroll
    for (int j = 0; j < 8; ++j) {
      atomicAdd(&s_sum[8 * ql + j], st[j]);
      atomicAdd(&s_sq[8 * ql + j], sqa[j]);
    }
  }
  __syncthreads();
  if (tid < 128) {
    atomicAdd(&stats[tid], s_sum[tid]);
    atomicAdd(&stats[128 + tid], s_sq[tid]);
  }
}

// ---------------------------------------------------------------- aggregation (F=64, final, bf16)
__global__ __launch_bounds__(256) void aggregate64_k(
    const unsigned short* __restrict__ Hb, const int* __restrict__ row_start,
    const int* __restrict__ deg, const int* __restrict__ csr_src,
    const float* __restrict__ dinv, const float* __restrict__ bias,
    float* __restrict__ outp) {
  int tid = threadIdx.x;
  int lane = tid & 63;
  int qt = lane >> 4;
  int ql = lane & 15;
  int nwaves = gridDim.x * (blockDim.x >> 6);
  int gwave = (int)((blockIdx.x * blockDim.x + tid) >> 6);
  const uint2* H2 = (const uint2*)Hb;  // 16 uint2 per row (cols 4ql..4ql+3)
  float4 b4 = ((const float4*)bias)[ql];
  auto accum = [](float (&a)[4], uint2 v) {
    a[0] += bf2f(v.x & 0xffffu); a[1] += bf2f(v.x >> 16);
    a[2] += bf2f(v.y & 0xffffu); a[3] += bf2f(v.y >> 16);
  };
  int node = gwave;
  int rs = 0, pd = 0;
  float di = 1.f;
  int ec = kN;
  if (node < kN) {
    rs = row_start[node];
    pd = (deg[node] + kPad - 1) & ~(kPad - 1);
    di = dinv[node];
    ec = csr_src[rs + lane];
  }
  while (node < kN) {
    int cur_rs = rs, cur_pd = pd, cur_e = ec;
    float cur_di = di;
    int nxt = node + nwaves;
    if (nxt < kN) {
      rs = row_start[nxt];
      pd = (deg[nxt] + kPad - 1) & ~(kPad - 1);
      di = dinv[nxt];
      ec = csr_src[rs + lane];
    }
    float a[4] = {0.f, 0.f, 0.f, 0.f};
    uint2 vself = H2[(size_t)node * 16 + ql];
    int nb = cur_pd >> 4;
    int nb4 = nb > 4 ? 4 : nb;
    for (int i = 0; i < nb4; ++i) {
      int s[4];
      uint2 v[4];
      #pragma unroll
      for (int j = 0; j < 4; ++j) s[j] = __shfl(cur_e, i * 16 + 4 * j + qt, 64);
      #pragma unroll
      for (int j = 0; j < 4; ++j) v[j] = H2[(size_t)s[j] * 16 + ql];
      #pragma unroll
      for (int j = 0; j < 4; ++j) accum(a, v[j]);
    }
    for (int i = 4; i < nb; ++i) {
      int ee = csr_src[cur_rs + i * 16 + (lane & 15)];
      int s[4];
      uint2 v[4];
      #pragma unroll
      for (int j = 0; j < 4; ++j) s[j] = __shfl(ee, 4 * j + qt, 64);
      #pragma unroll
      for (int j = 0; j < 4; ++j) v[j] = H2[(size_t)s[j] * 16 + ql];
      #pragma unroll
      for (int j = 0; j < 4; ++j) accum(a, v[j]);
    }
    #pragma unroll
    for (int j = 0; j < 4; ++j) {
      a[j] += __shfl_xor(a[j], 16, 64);
      a[j] += __shfl_xor(a[j], 32, 64);
    }
    accum(a, vself);
    if (qt == 0) {
      ((float4*)outp)[(size_t)node * 16 + ql] =
          make_float4(cur_di * a[0] + b4.x, cur_di * a[1] + b4.y,
                      cur_di * a[2] + b4.z, cur_di * a[3] + b4.w);
    }
    node = nxt;
  }
}

// ---------------------------------------------------------------- BN apply (finalize fused)
template <bool WRITE_Z, bool RF32>
__global__ void bn_apply_res_k(const unsigned int* __restrict__ a, const void* __restrict__ rp,
                               const float* __restrict__ stats, const float* __restrict__ g,
                               const float* __restrict__ be, unsigned int* __restrict__ z,
                               unsigned int* __restrict__ rb) {
  __shared__ float lss[256];
  int t = threadIdx.x;
  if (t < 128) {
    float mean = stats[t] * (1.f / kN);
    float var = stats[128 + t] * (1.f / kN) - mean * mean;
    float inv = rsqrtf(var + kEps);
    float sc = g[t] * inv;
    lss[t] = sc;
    lss[128 + t] = be[t] - mean * sc;
  }
  __syncthreads();
  int idx = blockIdx.x * blockDim.x + t;  // kN*16 groups of 8 bf16
  if (idx >= kN * 16) return;
  uint4 av = ((const uint4*)a)[idx];
  float r[8];
  if constexpr (RF32) {
    float4 r0 = ((const float4*)rp)[idx * 2];
    float4 r1 = ((const float4*)rp)[idx * 2 + 1];
    r[0] = r0.x; r[1] = r0.y; r[2] = r0.z; r[3] = r0.w;
    r[4] = r1.x; r[5] = r1.y; r[6] = r1.z; r[7] = r1.w;
  } else {
    uint4 rv = ((const uint4*)rp)[idx];
    r[0] = bf2f(rv.x & 0xffffu); r[1] = bf2f(rv.x >> 16);
    r[2] = bf2f(rv.y & 0xffffu); r[3] = bf2f(rv.y >> 16);
    r[4] = bf2f(rv.z & 0xffffu); r[5] = bf2f(rv.z >> 16);
    r[6] = bf2f(rv.w & 0xffffu); r[7] = bf2f(rv.w >> 16);
  }
  int c = (idx & 15) * 8;
  float o[8];
  unsigned int apk[4] = {av.x, av.y, av.z, av.w};
  #pragma unroll
  for (int j = 0; j < 4; ++j) {
    o[2 * j]     = lss[c + 2 * j] * bf2f(apk[j] & 0xffffu) + lss[128 + c + 2 * j] + r[2 * j];
    o[2 * j + 1] = lss[c + 2 * j + 1] * bf2f(apk[j] >> 16) + lss[128 + c + 2 * j + 1] + r[2 * j + 1];
  }
  if (WRITE_Z) {
    uint4 zv;
    zv.x = pack2bf(o[0], o[1]); zv.y = pack2bf(o[2], o[3]);
    zv.z = pack2bf(o[4], o[5]); zv.w = pack2bf(o[6], o[7]);
    ((uint4*)z)[idx] = zv;
  }
  uint4 hv;
  hv.x = pack2bf(fmaxf(o[0], 0.f), fmaxf(o[1], 0.f));
  hv.y = pack2bf(fmaxf(o[2], 0.f), fmaxf(o[3], 0.f));
  hv.z = pack2bf(fmaxf(o[4], 0.f), fmaxf(o[5], 0.f));
  hv.w = pack2bf(fmaxf(o[6], 0.f), fmaxf(o[7], 0.f));
  ((uint4*)rb)[idx] = hv;
}

// ---------------------------------------------------------------- launch
extern "C" void kernel_launch(void* const* d_in, const int* in_sizes, int n_in,
                              void* d_out, int out_size, void* d_ws, size_t ws_size,
                              hipStream_t stream) {
  const float* x   = (const float*)d_in[0];
  const int*   ei  = (const int*)d_in[1];
  const float* W1  = (const float*)d_in[2];
  const float* b1  = (const float*)d_in[3];
  const float* g1  = (const float*)d_in[4];
  const float* be1 = (const float*)d_in[5];
  const float* W2  = (const float*)d_in[6];
  const float* b2  = (const float*)d_in[7];
  const float* g2  = (const float*)d_in[8];
  const float* be2 = (const float*)d_in[9];
  const float* W3  = (const float*)d_in[10];
  const float* b3  = (const float*)d_in[11];
  float* outp = (float*)d_out;

  const int* src = ei;
  const int* dst = ei + kE;

  char* ws = (char*)d_ws;
  size_t off = 0;
  auto alloc = [&](size_t bytes) -> void* {
    void* p = ws + off;
    off = (off + bytes + 255) & ~size_t(255);
    return p;
  };
  // +1 row on H' buffers: dummy zero row at index kN for degree padding.
  unsigned char* hF8 = (unsigned char*)alloc((size_t)(kN + 1) * 128);      // H' fp8 (layers 1-2)
  unsigned short* hH = (unsigned short*)alloc((size_t)(kN + 1) * 64 * 2);  // H' bf16 (layer 3)
  unsigned int* aB = (unsigned int*)alloc((size_t)kN * 64 * 4);       // agg out (packed bf16)
  unsigned int* zC = (unsigned int*)alloc((size_t)kN * 64 * 4);       // z1 residual (packed bf16)
  unsigned int* hb = (unsigned int*)alloc((size_t)kN * 64 * 4);       // relu out / gemm in
  int*   csr_src  = (int*)alloc((size_t)(3200000 + 64) * 4);          // padded CSR + overread guard
  int2*  gstage   = (int2*)alloc((size_t)kNB * kBCAP * 8);            // ~19.3 MB
  // gcursor and counter in one block: one small memset covers both.
  int*   gcursor  = (int*)alloc((kNB + 1) * 4);
  int*   counter  = gcursor + kNB;
  int*   deg      = (int*)alloc((size_t)kN * 4);
  float* dinv     = (float*)alloc((size_t)kN * 4);
  int*   rowst    = (int*)alloc((size_t)kN * 4);
  float* stats    = (float*)alloc(256 * 4);
  unsigned short* wf1 = (unsigned short*)alloc(128 * 128 * 2);
  unsigned short* wf2 = (unsigned short*)alloc(128 * 128 * 2);
  unsigned short* wf3 = (unsigned short*)alloc(128 * 64 * 2);

  const int TB = 256;
  int blkBin = (kE + kCHUNK - 1) / kCHUNK;  // 391 (512 threads each)
  int blkGemm = (kN / 16 + 3) / 4;
  int blkApply = kN * 16 / TB;      // 6250
  const int blkAgg = 2048;

  // CSR build: memset(gcursor+counter) -> bin -> hist+alloc -> scatter
  hipMemsetAsync(gcursor, 0, (kNB + 1) * 4, stream);
  bin_k<<<blkBin, 512, 0, stream>>>(src, dst, gcursor, gstage);
  alloc_hist_k<<<kNB, TB, 0, stream>>>(gstage, gcursor, counter, deg, rowst, dinv);
  scatter2_k<<<kNB, TB, 0, stream>>>(gstage, gcursor, rowst, deg, csr_src);
  convert_w_all_k<<<21, TB, 0, stream>>>(W1, W2, W3, wf1, wf2, wf3, hF8, hH);

  // Layer 1 (A = fp32 x, residual = fp32 x); H' in fp8
  gemm_mfma_k<128, true, true><<<blkGemm, 256, 0, stream>>>(x, wf1, dinv, hF8, stats);
  aggregate128_k<<<blkAgg, TB, 0, stream>>>(hF8, rowst, deg, csr_src, dinv, b1, aB, stats);
  bn_apply_res_k<true, true><<<blkApply, TB, 0, stream>>>(aB, x, stats, g1, be1, zC, hb);

  // Layer 2 (residual = z1 bf16); H' in fp8
  gemm_mfma_k<128, false, true><<<blkGemm, 256, 0, stream>>>((const unsigned short*)hb, wf2, dinv, hF8, stats);
  aggregate128_k<<<blkAgg, TB, 0, stream>>>(hF8, rowst, deg, csr_src, dinv, b2, aB, stats);
  bn_apply_res_k<false, false><<<blkApply, TB, 0, stream>>>(aB, zC, stats, g2, be2, nullptr, hb);

  // Layer 3: H' in bf16 (final output path — keep precision)
  gemm_mfma_k<64, false, false><<<blkGemm, 256, 0, stream>>>((const unsigned short*)hb, wf3, dinv, hH, nullptr);
  aggregate64_k<<<blkAgg, TB, 0, stream>>>(hH, rowst, deg, csr_src, dinv, b3, outp);
}